// Round 15
// baseline (1101.317 us; speedup 1.0000x reference)
//
#include <hip/hip_runtime.h>

#define T_STEPS 4
#define BATCH   8
#define C_IN    64
#define C_OUT   64
#define HH      128
#define WW      128
#define TH      4
#define TW      16
#define ROWS    (TH + 2)    // 6
#define COLS    18          // staged columns (halo)
#define RLEN    24          // padded row pitch (words) -> measured-conflict-free b32 pattern

// f32 rounding of math.exp(-0.5)
#define DECAY_F32 0.6065306597126334f

// Weight re-layout: w[co][ci][ky][kx] -> wt[j][ci][co], j = ky*3+kx
__global__ void wt_build_kernel(const float* __restrict__ w, float* __restrict__ wt) {
    int tid = blockIdx.x * blockDim.x + threadIdx.x;
    if (tid >= 9 * C_IN * C_OUT) return;
    int co = tid & 63;
    int ci = (tid >> 6) & 63;
    int j  = tid >> 12;
    wt[tid] = w[(co * C_IN + ci) * 9 + j];
}

// Exact replica of the reference f32 arithmetic (probe-verified variant A):
// per output: seq FMA chain over (ky,kx, ci-innermost); cb = acc+bias;
// vt = v*DECAY + cb (separate rounded mul/add); spike = vt>1; soft reset.
//
// Block = 256 thr = 4 waves; wave w owns co [16w,16w+16). Lane owns ONE pixel
// (y = lane&3, x = lane>>2) of the 16x4 tile and 16 c_out.
// Per (tap,ci): one ds_read_b32 (r11's measured-conflict-free mapping: bank =
// (24y + x) mod 32 covers each bank exactly 2x per wave = free) + 16 FMA with
// SGPR-broadcast weights (wave-uniform address -> s_load_dwordx16).
// LDS 36864 B -> 4 blocks/CU -> 16 waves/CU across 4 independent blocks
// (barrier stagger; r12's idle came from only 2 correlated blocks).
__global__ __launch_bounds__(256, 4) void snn_exact_kernel(
    const float* __restrict__ x,    // [T,B,C_IN,H,W]
    const float* __restrict__ wt,   // [9][C_IN][C_OUT]
    const float* __restrict__ bias, // [C_OUT]
    float* __restrict__ out)        // [T,B,C_OUT,H,W]
{
    __shared__ __align__(16) float sx[C_IN][ROWS][RLEN];   // 36864 B

    const int tid  = threadIdx.x;
    const int wid  = __builtin_amdgcn_readfirstlane(tid >> 6); // 0..3 (SGPR)
    const int lane = tid & 63;
    const int y    = lane & 3;          // 0..3
    const int xcol = lane >> 2;         // 0..15
    const int cob  = wid << 4;          // wave's co base: 0,16,32,48
    const int b    = blockIdx.z;
    const int gy0  = blockIdx.y * TH;
    const int gx0  = blockIdx.x * TW;

    const float* bp = bias + cob;       // wave-uniform -> SGPR

    float v[16];
#pragma unroll
    for (int o = 0; o < 16; ++o) v[o] = 0.0f;

    for (int t = 0; t < T_STEPS; ++t) {
        __syncthreads();  // prior t's reads done before overwrite
        const float* xsrc = x + ((size_t)(t * BATCH + b) * C_IN) * (HH * WW);
        for (int e = tid; e < C_IN * ROWS * COLS; e += 256) {
            int ci  = e / (ROWS * COLS);
            int rem = e - ci * (ROWS * COLS);
            int row = rem / COLS;
            int col = rem - row * COLS;
            int gy  = gy0 + row - 1;
            int gx  = gx0 + col - 1;
            float val = 0.0f;
            if ((unsigned)gy < (unsigned)HH && (unsigned)gx < (unsigned)WW)
                val = xsrc[ci * (HH * WW) + gy * WW + gx];
            sx[ci][row][col] = val;
        }
        __syncthreads();

        float acc[16];
#pragma unroll
        for (int o = 0; o < 16; ++o) acc[o] = 0.0f;

// One conv tap: ci 0..63 sequential (exact chain order). One ds_read_b32 per
// ci (address folds to base + 16-bit immediate), 16 FMAs with SGPR weights.
#define TAP(KY, KX)                                                                   \
        {                                                                             \
            const float* wj = wt + ((KY) * 3 + (KX)) * (C_IN * C_OUT) + cob;          \
            _Pragma("unroll 4")                                                       \
            for (int ci = 0; ci < C_IN; ++ci) {                                       \
                const float xv = sx[ci][y + (KY)][xcol + (KX)];                       \
                const float* wp = wj + (ci << 6);                                     \
                _Pragma("unroll")                                                     \
                for (int o = 0; o < 16; ++o)                                          \
                    acc[o] = fmaf(xv, wp[o], acc[o]);                                 \
            }                                                                         \
        }

        TAP(0, 0) TAP(0, 1) TAP(0, 2)
        TAP(1, 0) TAP(1, 1) TAP(1, 2)
        TAP(2, 0) TAP(2, 1) TAP(2, 2)
#undef TAP

        // ---- LIF update (exact f32 op sequence) + spike store ----
        float* obase = out + ((size_t)(t * BATCH + b) * C_OUT + cob) * (HH * WW)
                     + (gy0 + y) * WW + gx0 + xcol;
#pragma unroll
        for (int o = 0; o < 16; ++o) {
            float cb = __fadd_rn(acc[o], bp[o]);                  // conv + bias (SGPR)
            float vt = __fadd_rn(__fmul_rn(v[o], DECAY_F32), cb); // v*DECAY + cb
            bool fire = vt > 1.0f;
            v[o] = fire ? 0.0f : vt;                              // soft reset
            obase[(size_t)o * (HH * WW)] = fire ? 1.0f : 0.0f;
        }
    }
}

extern "C" void kernel_launch(void* const* d_in, const int* in_sizes, int n_in,
                              void* d_out, int out_size, void* d_ws, size_t ws_size,
                              hipStream_t stream) {
    const float* x    = (const float*)d_in[0];
    const float* w    = (const float*)d_in[1];
    const float* bias = (const float*)d_in[2];
    float* out = (float*)d_out;
    float* wt  = (float*)d_ws;   // 9*64*64*4 = 147456 bytes

    hipLaunchKernelGGL(wt_build_kernel, dim3((9 * C_IN * C_OUT + 255) / 256), dim3(256), 0, stream, w, wt);
    hipLaunchKernelGGL(snn_exact_kernel, dim3(WW / TW, HH / TH, BATCH), dim3(256), 0, stream,
                       x, wt, bias, out);
}

// Round 16
// 580.054 us; speedup vs baseline: 1.8986x; 1.8986x over previous
//
#include <hip/hip_runtime.h>

#define T_STEPS 4
#define BATCH   8
#define C_IN    64
#define C_OUT   64
#define HH      128
#define WW      128
#define TH      4
#define TW      16
#define ROWS    (TH + 2)     // 6
#define COLS    18           // staged columns (halo)
#define PAIRS   (C_IN / 2)   // 32 ci-pairs
#define RPITCH  48           // words per row: 24 col-slots x 2 ci-parities

// f32 rounding of math.exp(-0.5)
#define DECAY_F32 0.6065306597126334f

// Weight re-layout: w[co][ci][ky][kx] -> wt[j][ci][co], j = ky*3+kx
__global__ void wt_build_kernel(const float* __restrict__ w, float* __restrict__ wt) {
    int tid = blockIdx.x * blockDim.x + threadIdx.x;
    if (tid >= 9 * C_IN * C_OUT) return;
    int co = tid & 63;
    int ci = (tid >> 6) & 63;
    int j  = tid >> 12;
    wt[tid] = w[(co * C_IN + ci) * 9 + j];
}

// Exact replica of the reference f32 arithmetic (probe-verified variant A):
// per output: seq FMA chain over (ky,kx, ci-innermost); cb = acc+bias;
// vt = v*DECAY + cb (separate rounded mul/add); spike = vt>1; soft reset.
//
// r11 configuration (the measured best: 8-wave blocks, 8 co/lane, 36KB LDS,
// 4 blocks/CU = 32 waves/CU) with ONE change: x is stored ci-PAIRED in LDS
// (sx[cip][row][col*2+parity]) so each (tap, ci-pair) does a single
// ds_read_b64 feeding 16 FMAs (ci then ci+1 -> chain order intact).
// Bank check: word addr = cip*288 + row*48 + col*2 (+parity); per half-wave
// (y 0..3 bases {0,16,0,16}, x stride 2) every bank is hit exactly 2x =
// the b64 minimum -> conflict-free. Weights wave-uniform -> s_load (SGPR).
__global__ __launch_bounds__(512, 8) void snn_exact_kernel(
    const float* __restrict__ x,    // [T,B,C_IN,H,W]
    const float* __restrict__ wt,   // [9][C_IN][C_OUT]
    const float* __restrict__ bias, // [C_OUT]
    float* __restrict__ out)        // [T,B,C_OUT,H,W]
{
    __shared__ __align__(16) float sx[PAIRS * ROWS * RPITCH];   // 36864 B

    const int tid  = threadIdx.x;
    const int wid  = __builtin_amdgcn_readfirstlane(tid >> 6); // 0..7 (SGPR)
    const int lane = tid & 63;
    const int y    = lane & 3;          // 0..3
    const int xcol = lane >> 2;         // 0..15
    const int cob  = wid << 3;          // wave's co base: 0,8,...,56
    const int b    = blockIdx.z;
    const int gy0  = blockIdx.y * TH;
    const int gx0  = blockIdx.x * TW;

    const float* bp = bias + cob;       // wave-uniform -> SGPR

    float v[8];
#pragma unroll
    for (int o = 0; o < 8; ++o) v[o] = 0.0f;

    for (int t = 0; t < T_STEPS; ++t) {
        __syncthreads();  // prior t's reads done before overwrite
        const float* xsrc = x + ((size_t)(t * BATCH + b) * C_IN) * (HH * WW);
        // stage: e = (cip, row, col); each thread loads the ci-pair (2 scalar
        // global reads, 64KB apart) and writes one ds_write_b64.
        for (int e = tid; e < PAIRS * ROWS * COLS; e += 512) {
            int cip = e / (ROWS * COLS);
            int rem = e - cip * (ROWS * COLS);
            int row = rem / COLS;
            int col = rem - row * COLS;
            int gy  = gy0 + row - 1;
            int gx  = gx0 + col - 1;
            float2 val = {0.f, 0.f};
            if ((unsigned)gy < (unsigned)HH && (unsigned)gx < (unsigned)WW) {
                const float* g = xsrc + (size_t)(cip << 1) * (HH * WW) + gy * WW + gx;
                val.x = g[0];
                val.y = g[HH * WW];
            }
            *reinterpret_cast<float2*>(&sx[(cip * ROWS + row) * RPITCH + (col << 1)]) = val;
        }
        __syncthreads();

        float acc[8];
#pragma unroll
        for (int o = 0; o < 8; ++o) acc[o] = 0.0f;

// One conv tap: ci-pairs 0..31 ascending; per pair one ds_read_b64 then
// 8 FMA (even ci) + 8 FMA (odd ci) -> exact (ky,kx,ci) chain order.
#define TAP(KY, KX)                                                                   \
        {                                                                             \
            const float* wj = wt + ((KY) * 3 + (KX)) * (C_IN * C_OUT) + cob;          \
            const float* xb = &sx[(y + (KY)) * RPITCH + ((xcol + (KX)) << 1)];        \
            _Pragma("unroll 4")                                                       \
            for (int cip = 0; cip < PAIRS; ++cip) {                                   \
                const float2 xv = *reinterpret_cast<const float2*>(xb + cip * (ROWS * RPITCH)); \
                const float* wp0 = wj + ((cip << 1) << 6);                            \
                const float* wp1 = wp0 + C_OUT;                                       \
                _Pragma("unroll")                                                     \
                for (int o = 0; o < 8; ++o) acc[o] = fmaf(xv.x, wp0[o], acc[o]);      \
                _Pragma("unroll")                                                     \
                for (int o = 0; o < 8; ++o) acc[o] = fmaf(xv.y, wp1[o], acc[o]);      \
            }                                                                         \
        }

        TAP(0, 0) TAP(0, 1) TAP(0, 2)
        TAP(1, 0) TAP(1, 1) TAP(1, 2)
        TAP(2, 0) TAP(2, 1) TAP(2, 2)
#undef TAP

        // ---- LIF update (exact f32 op sequence) + spike store ----
        float* obase = out + ((size_t)(t * BATCH + b) * C_OUT + cob) * (HH * WW)
                     + (gy0 + y) * WW + gx0 + xcol;
#pragma unroll
        for (int o = 0; o < 8; ++o) {
            float cb = __fadd_rn(acc[o], bp[o]);                  // conv + bias (SGPR)
            float vt = __fadd_rn(__fmul_rn(v[o], DECAY_F32), cb); // v*DECAY + cb
            bool fire = vt > 1.0f;
            v[o] = fire ? 0.0f : vt;                              // soft reset
            obase[(size_t)o * (HH * WW)] = fire ? 1.0f : 0.0f;
        }
    }
}

extern "C" void kernel_launch(void* const* d_in, const int* in_sizes, int n_in,
                              void* d_out, int out_size, void* d_ws, size_t ws_size,
                              hipStream_t stream) {
    const float* x    = (const float*)d_in[0];
    const float* w    = (const float*)d_in[1];
    const float* bias = (const float*)d_in[2];
    float* out = (float*)d_out;
    float* wt  = (float*)d_ws;   // 9*64*64*4 = 147456 bytes

    hipLaunchKernelGGL(wt_build_kernel, dim3((9 * C_IN * C_OUT + 255) / 256), dim3(256), 0, stream, w, wt);
    hipLaunchKernelGGL(snn_exact_kernel, dim3(WW / TW, HH / TH, BATCH), dim3(512), 0, stream,
                       x, wt, bias, out);
}